// Round 6
// baseline (2168.552 us; speedup 1.0000x reference)
//
#include <hip/hip_runtime.h>
#include <math.h>

#define NB 4
#define NT 25
#define NN 10000
#define NF 3
#define NC 16
#define NE 160000
#define HID 512
#define NOUT 2
#define FLAT (NN*NC)    // 160000

// head1 split: 500 blocks x 320 rows, 2 half-chunks each -> 1000 partial chunks
#define NHB 500
#define HCHUNK 320
#define NPART (NHB*2)
#define RSPLIT 16
#define RSPAN ((NPART + RSPLIT - 1)/RSPLIT)   // 63

// ---------------- CSR build (deterministic float math: no float atomics) ----------------

__global__ void k_init(int* count, int* cursor) {
    int n = blockIdx.x*blockDim.x + threadIdx.x;
    if (n < NN) { count[n] = 0; cursor[n] = 0; }
}

__global__ void k_count(const int* ei, int* count) {
    int e = blockIdx.x*blockDim.x + threadIdx.x;
    if (e < NE) atomicAdd(&count[ei[NE + e]], 1);
}

__global__ __launch_bounds__(1024) void k_scan(const int* count, int* rowptr) {
    __shared__ int wsum[16];
    __shared__ int carry;
    int tid = threadIdx.x;
    if (tid == 0) { carry = 0; rowptr[0] = 0; }
    __syncthreads();
    for (int base = 0; base < NN; base += 1024) {
        int i = base + tid;
        int v = (i < NN) ? count[i] : 0;
        int lane = tid & 63, wid = tid >> 6;
        int xs = v;
        #pragma unroll
        for (int off = 1; off < 64; off <<= 1) {
            int y = __shfl_up(xs, off);
            if (lane >= off) xs += y;
        }
        if (lane == 63) wsum[wid] = xs;
        __syncthreads();
        if (wid == 0 && lane < 16) {
            int s = wsum[lane];
            #pragma unroll
            for (int off = 1; off < 16; off <<= 1) {
                int y = __shfl_up(s, off);
                if (lane >= off) s += y;
            }
            wsum[lane] = s;
        }
        __syncthreads();
        int prefix = carry + (wid ? wsum[wid-1] : 0);
        if (i < NN) rowptr[i+1] = prefix + xs;
        __syncthreads();
        if (tid == 0) carry += wsum[15];
        __syncthreads();
    }
}

__global__ void k_fill(const int* ei, const float* ew, const int* rowptr,
                       int* cursor, int* col, float* val) {
    int e = blockIdx.x*blockDim.x + threadIdx.x;
    if (e < NE) {
        int src = ei[e];
        int dst = ei[NE + e];
        int p = rowptr[dst] + atomicAdd(&cursor[dst], 1);
        col[p] = src;
        val[p] = ew[e];          // raw weight; normalized after deg
    }
}

__global__ void k_deg(const int* rowptr, const float* val, float* dinv) {
    int n = blockIdx.x*blockDim.x + threadIdx.x;
    if (n >= NN) return;
    float d = 1.0f;              // self loop weight
    int beg = rowptr[n], end = rowptr[n+1];
    for (int j = beg; j < end; ++j) d += val[j];
    dinv[n] = (d > 0.f) ? 1.0f/sqrtf(d) : 0.f;
}

__global__ void k_norm(const int* rowptr, const int* col, const float* dinv, float* val) {
    int n = blockIdx.x*blockDim.x + threadIdx.x;
    if (n >= NN) return;
    float dn = dinv[n];
    int beg = rowptr[n], end = rowptr[n+1];
    for (int j = beg; j < end; ++j) val[j] = dinv[col[j]] * val[j] * dn;
}

// ---------------- x repack: xp[t][n][b] = float4(x[b,t,n,0..2], 0) ----------------

__global__ __launch_bounds__(256) void k_xpad(const float* x, float4* xp) {
    int idx = blockIdx.x*blockDim.x + threadIdx.x;
    if (idx >= NN*NT) return;
    int n = idx % NN;
    int t = idx / NN;
    #pragma unroll
    for (int b = 0; b < NB; ++b) {
        int base = ((b*NT + t)*NN + n)*NF;
        float4 o; o.x = x[base]; o.y = x[base+1]; o.z = x[base+2]; o.w = 0.f;
        xp[(t*NN + n)*NB + b] = o;
    }
}

// ---------------- aggregation: agg[t][b][n] = (A_hat x_t)[b,n,:] ----------------

__global__ __launch_bounds__(256) void k_agg(const float4* xp, const int* rowptr, const int* col,
                                             const float* val, const float* dinv, float4* agg) {
    int idx = blockIdx.x*blockDim.x + threadIdx.x;
    if (idx >= NN*NT) return;
    int n = idx % NN;
    int t = idx / NN;
    float di = dinv[n];
    float dsq = di*di;                 // self-loop: w=1, norm = dinv[n]^2
    float ax[NB], ay[NB], az[NB];
    int sbase = (t*NN + n)*NB;
    #pragma unroll
    for (int b = 0; b < NB; ++b) {
        float4 v = xp[sbase + b];
        ax[b] = dsq*v.x; ay[b] = dsq*v.y; az[b] = dsq*v.z;
    }
    int beg = rowptr[n], end = rowptr[n+1];
    int j = beg;
    for (; j + 1 < end; j += 2) {       // 2x unroll: 8 independent gathers in flight
        int s0 = col[j],   s1 = col[j+1];
        float nv0 = val[j], nv1 = val[j+1];
        int g0 = (t*NN + s0)*NB, g1 = (t*NN + s1)*NB;
        #pragma unroll
        for (int b = 0; b < NB; ++b) {
            float4 v0 = xp[g0 + b];
            float4 v1 = xp[g1 + b];
            ax[b] += nv0*v0.x + nv1*v1.x;
            ay[b] += nv0*v0.y + nv1*v1.y;
            az[b] += nv0*v0.z + nv1*v1.z;
        }
    }
    if (j < end) {
        int s = col[j];
        float nv = val[j];
        int gb = (t*NN + s)*NB;
        #pragma unroll
        for (int b = 0; b < NB; ++b) {
            float4 v = xp[gb + b];
            ax[b] += nv*v.x; ay[b] += nv*v.y; az[b] += nv*v.z;
        }
    }
    #pragma unroll
    for (int b = 0; b < NB; ++b) {
        float4 o; o.x = ax[b]; o.y = ay[b]; o.z = az[b]; o.w = 0.f;
        agg[(t*NB + b)*NN + n] = o;
    }
}

// ---------------- fused GRU: all 25 steps, H in registers ----------------
// sF float layout per gate g (base g*320):
//   [0..47]  W' = W@L_top, index f*16+c      -> as float4: elem f*4+q
//   [48..63] b' = b@L_top + lb               -> as float4: elem 12+q
//   [64..319] L_bot, index k*16+c            -> as float4: elem 16+k*4+q

__device__ __forceinline__ float4 f4fma(float s, float4 w, float4 a) {
    a.x = fmaf(s, w.x, a.x); a.y = fmaf(s, w.y, a.y);
    a.z = fmaf(s, w.z, a.z); a.w = fmaf(s, w.w, a.w);
    return a;
}

__global__ __launch_bounds__(256, 2) void k_gru_all(
        const float* Wz, const float* bz, const float* Lz, const float* lbz,
        const float* Wr, const float* br, const float* Lr, const float* lbr,
        const float* Wh, const float* bh, const float* Lh, const float* lbh,
        const float4* agg, float* H) {
    __shared__ float sF[960];
    {
        int tid = threadIdx.x;
        const float* W[3]  = {Wz, Wr, Wh};
        const float* bb[3] = {bz, br, bh};
        const float* L[3]  = {Lz, Lr, Lh};
        const float* lb[3] = {lbz, lbr, lbh};
        #pragma unroll
        for (int g = 0; g < 3; ++g) {
            float* outp = sF + g*320;
            if (tid < 48) {
                int f = tid >> 4, c = tid & 15;
                float s = 0.f;
                #pragma unroll
                for (int k = 0; k < 16; ++k) s += W[g][f*16+k] * L[g][k*16+c];
                outp[tid] = s;
            }
            if (tid < 16) {
                float s = 0.f;
                #pragma unroll
                for (int k = 0; k < 16; ++k) s += bb[g][k] * L[g][k*16+tid];
                outp[48+tid] = s + lb[g][tid];
            }
            {
                int k = tid >> 4, c = tid & 15;
                outp[64 + tid] = L[g][(16+k)*16 + c];
            }
        }
    }
    __syncthreads();
    int idx = blockIdx.x*blockDim.x + threadIdx.x;
    if (idx >= NB*NN) return;
    int b = idx / NN, n = idx % NN;
    const float4* Fz = (const float4*)(sF);
    const float4* Fr = (const float4*)(sF + 320);
    const float4* Fh = (const float4*)(sF + 640);

    float Hv[16];
    #pragma unroll
    for (int c = 0; c < 16; ++c) Hv[c] = 0.f;

    float4 Acur = agg[(size_t)b*NN + n];            // t = 0
    for (int t = 0; t < NT; ++t) {
        float4 Anext = Acur;
        if (t + 1 < NT) Anext = agg[((t+1)*NB + b)*NN + n];   // prefetch: hides under gate math

        // ---- phase 1: z and r quads (share Hv[k] broadcast) ----
        float4 zq[4], rq[4];
        #pragma unroll
        for (int q = 0; q < 4; ++q) {
            zq[q] = f4fma(Acur.x, Fz[q], f4fma(Acur.y, Fz[4+q], f4fma(Acur.z, Fz[8+q], Fz[12+q])));
            rq[q] = f4fma(Acur.x, Fr[q], f4fma(Acur.y, Fr[4+q], f4fma(Acur.z, Fr[8+q], Fr[12+q])));
        }
        #pragma unroll
        for (int k = 0; k < 16; ++k) {
            float hk = Hv[k];
            #pragma unroll
            for (int q = 0; q < 4; ++q) {
                zq[q] = f4fma(hk, Fz[16 + k*4 + q], zq[q]);
                rq[q] = f4fma(hk, Fr[16 + k*4 + q], rq[q]);
            }
        }
        // ---- phase 2: sigmoids; collapse r into scalar rH[k] = Hv[k]*sig(r[k]) ----
        float rH[16];
        #pragma unroll
        for (int q = 0; q < 4; ++q) {
            zq[q].x = 1.f/(1.f+expf(-zq[q].x));
            zq[q].y = 1.f/(1.f+expf(-zq[q].y));
            zq[q].z = 1.f/(1.f+expf(-zq[q].z));
            zq[q].w = 1.f/(1.f+expf(-zq[q].w));
            rH[q*4+0] = Hv[q*4+0] * (1.f/(1.f+expf(-rq[q].x)));
            rH[q*4+1] = Hv[q*4+1] * (1.f/(1.f+expf(-rq[q].y)));
            rH[q*4+2] = Hv[q*4+2] * (1.f/(1.f+expf(-rq[q].z)));
            rH[q*4+3] = Hv[q*4+3] * (1.f/(1.f+expf(-rq[q].w)));
        }
        // ---- phase 3: ht quads ----
        float4 hq[4];
        #pragma unroll
        for (int q = 0; q < 4; ++q)
            hq[q] = f4fma(Acur.x, Fh[q], f4fma(Acur.y, Fh[4+q], f4fma(Acur.z, Fh[8+q], Fh[12+q])));
        #pragma unroll
        for (int k = 0; k < 16; ++k) {
            float hk = rH[k];
            #pragma unroll
            for (int q = 0; q < 4; ++q) hq[q] = f4fma(hk, Fh[16 + k*4 + q], hq[q]);
        }
        // ---- phase 4: combine ----
        #pragma unroll
        for (int q = 0; q < 4; ++q) {
            Hv[q*4+0] = zq[q].x*Hv[q*4+0] + (1.f-zq[q].x)*tanhf(hq[q].x);
            Hv[q*4+1] = zq[q].y*Hv[q*4+1] + (1.f-zq[q].y)*tanhf(hq[q].y);
            Hv[q*4+2] = zq[q].z*Hv[q*4+2] + (1.f-zq[q].z)*tanhf(hq[q].z);
            Hv[q*4+3] = zq[q].w*Hv[q*4+3] + (1.f-zq[q].w)*tanhf(hq[q].w);
        }
        Acur = Anext;
    }
    int hbase = (b*NN + n)*NC;
    #pragma unroll
    for (int c = 0; c < 16; ++c) H[hbase+c] = Hv[c];
}

// ---------------- head: H(4,160000) @ W1(160000,512), split-K, float4 loads ----------------

__global__ __launch_bounds__(256) void k_head1(const float* H, const float* W1, float* part) {
    __shared__ float sH[NB][HCHUNK];
    int chunk = blockIdx.x;
    int i0 = chunk * HCHUNK;
    for (int i = threadIdx.x; i < NB*HCHUNK; i += 256) {
        int b = i / HCHUNK, r = i % HCHUNK;
        sH[b][r] = H[b*FLAT + i0 + r];
    }
    __syncthreads();
    int half = threadIdx.x >> 7;        // which row parity this thread sums
    int jj = (threadIdx.x & 127) * 4;   // column group
    const float* Wb = W1 + (size_t)i0*HID + jj;
    float acc[NB][4] = {};
    for (int r0 = half; r0 < HCHUNK; r0 += 16) {
        float4 w0 = *(const float4*)(Wb + (size_t)(r0     )*HID);
        float4 w1 = *(const float4*)(Wb + (size_t)(r0 +  2)*HID);
        float4 w2 = *(const float4*)(Wb + (size_t)(r0 +  4)*HID);
        float4 w3 = *(const float4*)(Wb + (size_t)(r0 +  6)*HID);
        float4 w4 = *(const float4*)(Wb + (size_t)(r0 +  8)*HID);
        float4 w5 = *(const float4*)(Wb + (size_t)(r0 + 10)*HID);
        float4 w6 = *(const float4*)(Wb + (size_t)(r0 + 12)*HID);
        float4 w7 = *(const float4*)(Wb + (size_t)(r0 + 14)*HID);
        #pragma unroll
        for (int b = 0; b < NB; ++b) {
            float h0 = sH[b][r0],    h1 = sH[b][r0+2],  h2 = sH[b][r0+4],  h3 = sH[b][r0+6];
            float h4 = sH[b][r0+8],  h5 = sH[b][r0+10], h6 = sH[b][r0+12], h7 = sH[b][r0+14];
            acc[b][0] += h0*w0.x + h1*w1.x + h2*w2.x + h3*w3.x + h4*w4.x + h5*w5.x + h6*w6.x + h7*w7.x;
            acc[b][1] += h0*w0.y + h1*w1.y + h2*w2.y + h3*w3.y + h4*w4.y + h5*w5.y + h6*w6.y + h7*w7.y;
            acc[b][2] += h0*w0.z + h1*w1.z + h2*w2.z + h3*w3.z + h4*w4.z + h5*w5.z + h6*w6.z + h7*w7.z;
            acc[b][3] += h0*w0.w + h1*w1.w + h2*w2.w + h3*w3.w + h4*w4.w + h5*w5.w + h6*w6.w + h7*w7.w;
        }
    }
    int pc = chunk*2 + half;
    #pragma unroll
    for (int q = 0; q < 4; ++q)
        #pragma unroll
        for (int b = 0; b < NB; ++b)
            part[((size_t)pc*HID + jj + q)*NB + b] = acc[b][q];
}

// phase 1: split the 1000-chunk sum 16 ways, float4-wide (8192 threads)
__global__ void k_reduce1(const float4* part, float4* part2) {
    int idx = blockIdx.x*blockDim.x + threadIdx.x;   // 0 .. RSPLIT*512-1
    if (idx >= RSPLIT*512) return;
    int k = idx >> 9;            // split index
    int jq = idx & 511;          // float4 lane within the 2048-float row
    int c0 = k*RSPAN;
    int c1 = c0 + RSPAN; if (c1 > NPART) c1 = NPART;
    float4 s = make_float4(0.f, 0.f, 0.f, 0.f);
    for (int c = c0; c < c1; ++c) {
        float4 v = part[(size_t)c*512 + jq];
        s.x += v.x; s.y += v.y; s.z += v.z; s.w += v.w;
    }
    part2[k*512 + jq] = s;
}

// phase 2 + final head, one block: h1 = leaky(sum + b1); out = h1 @ W2 + b2
__global__ __launch_bounds__(256) void k_reduce2final(const float* part2, const float* b1,
                                                      const float* W2, const float* b2, float* out) {
    __shared__ float sH1[HID*NB];        // [j*4+b]
    __shared__ float sred[4][8];
    int tid = threadIdx.x;
    #pragma unroll
    for (int i = 0; i < 8; ++i) {
        int jb = tid + i*256;
        int j = jb >> 2;
        float s = 0.f;
        #pragma unroll
        for (int k = 0; k < RSPLIT; ++k) s += part2[k*(HID*NB) + jb];
        s += b1[j];
        s = (s > 0.f) ? s : 0.01f*s;     // LeakyReLU(0.01)
        sH1[jb] = s;
    }
    __syncthreads();
    float p[8] = {};                      // [b*2+o]
    #pragma unroll
    for (int rep = 0; rep < 2; ++rep) {
        int j = tid + rep*256;
        float w0 = W2[j*NOUT], w1 = W2[j*NOUT+1];
        #pragma unroll
        for (int b = 0; b < NB; ++b) {
            float hv = sH1[j*4 + b];
            p[b*2]   += hv*w0;
            p[b*2+1] += hv*w1;
        }
    }
    int lane = tid & 63, wid = tid >> 6;
    #pragma unroll
    for (int i = 0; i < 8; ++i) {
        #pragma unroll
        for (int off = 32; off > 0; off >>= 1) p[i] += __shfl_xor(p[i], off);
    }
    if (lane == 0)
        #pragma unroll
        for (int i = 0; i < 8; ++i) sred[wid][i] = p[i];
    __syncthreads();
    if (tid < 8) {
        float s = sred[0][tid] + sred[1][tid] + sred[2][tid] + sred[3][tid];
        out[tid] = s + b2[tid & 1];
    }
}

// ---------------- launch ----------------

extern "C" void kernel_launch(void* const* d_in, const int* in_sizes, int n_in,
                              void* d_out, int out_size, void* d_ws, size_t ws_size,
                              hipStream_t stream) {
    const float* x   = (const float*)d_in[0];
    const int*   ei  = (const int*)d_in[1];
    const float* ew  = (const float*)d_in[2];
    const float* Wz  = (const float*)d_in[3];
    const float* bz  = (const float*)d_in[4];
    const float* Lz  = (const float*)d_in[5];
    const float* lbz = (const float*)d_in[6];
    const float* Wr  = (const float*)d_in[7];
    const float* br  = (const float*)d_in[8];
    const float* Lr  = (const float*)d_in[9];
    const float* lbr = (const float*)d_in[10];
    const float* Wh  = (const float*)d_in[11];
    const float* bh  = (const float*)d_in[12];
    const float* Lh  = (const float*)d_in[13];
    const float* lbh = (const float*)d_in[14];
    const float* W1  = (const float*)d_in[15];
    const float* b1  = (const float*)d_in[16];
    const float* W2  = (const float*)d_in[17];
    const float* b2  = (const float*)d_in[18];
    float* out = (float*)d_out;

    char* base = (char*)d_ws;
    size_t off = 0;
    auto alloc = [&](size_t bytes) -> char* {
        char* p = base + off;
        off = (off + bytes + 255) & ~(size_t)255;
        return p;
    };
    float*  dinv   = (float*)alloc(NN*sizeof(float));
    int*    count  = (int*)  alloc(NN*sizeof(int));
    int*    rowptr = (int*)  alloc((NN+1)*sizeof(int));
    int*    cursor = (int*)  alloc(NN*sizeof(int));
    int*    col    = (int*)  alloc(NE*sizeof(int));
    float*  val    = (float*)alloc(NE*sizeof(float));
    float4* xp     = (float4*)alloc((size_t)NT*NN*NB*sizeof(float4));
    float4* agg    = (float4*)alloc((size_t)NT*NB*NN*sizeof(float4));
    float*  H      = (float*)alloc((size_t)NB*NN*NC*sizeof(float));
    float*  part   = (float*)alloc((size_t)NPART*HID*NB*sizeof(float));
    float*  part2  = (float*)alloc((size_t)RSPLIT*HID*NB*sizeof(float));
    (void)ws_size; (void)n_in; (void)in_sizes; (void)out_size;

    k_init<<<(NN+255)/256, 256, 0, stream>>>(count, cursor);
    k_count<<<(NE+255)/256, 256, 0, stream>>>(ei, count);
    k_scan<<<1, 1024, 0, stream>>>(count, rowptr);
    k_fill<<<(NE+255)/256, 256, 0, stream>>>(ei, ew, rowptr, cursor, col, val);
    k_deg<<<(NN+255)/256, 256, 0, stream>>>(rowptr, val, dinv);
    k_norm<<<(NN+255)/256, 256, 0, stream>>>(rowptr, col, dinv, val);
    k_xpad<<<(NN*NT+255)/256, 256, 0, stream>>>(x, xp);
    k_agg<<<(NN*NT+255)/256, 256, 0, stream>>>(xp, rowptr, col, val, dinv, agg);
    k_gru_all<<<(NB*NN+255)/256, 256, 0, stream>>>(Wz, bz, Lz, lbz, Wr, br, Lr, lbr,
                                                   Wh, bh, Lh, lbh, agg, H);
    k_head1<<<NHB, 256, 0, stream>>>(H, W1, part);
    k_reduce1<<<(RSPLIT*512+255)/256, 256, 0, stream>>>((const float4*)part, (float4*)part2);
    k_reduce2final<<<1, 256, 0, stream>>>(part2, b1, W2, b2, out);
}

// Round 9
// 725.066 us; speedup vs baseline: 2.9908x; 2.9908x over previous
//
#include <hip/hip_runtime.h>
#include <math.h>

#define NB 4
#define NT 25
#define NN 10000
#define NF 3
#define NC 16
#define NE 160000
#define HID 512
#define NOUT 2
#define FLAT (NN*NC)    // 160000

// head1 split: 500 blocks x 320 rows, 2 half-chunks each -> 1000 partial chunks
#define NHB 500
#define HCHUNK 320
#define NPART (NHB*2)
#define RSPLIT 16
#define RSPAN ((NPART + RSPLIT - 1)/RSPLIT)   // 63

// ---------------- CSR build (deterministic float math: no float atomics) ----------------

__global__ void k_init(int* count, int* cursor) {
    int n = blockIdx.x*blockDim.x + threadIdx.x;
    if (n < NN) { count[n] = 0; cursor[n] = 0; }
}

__global__ void k_count(const int* ei, int* count) {
    int e = blockIdx.x*blockDim.x + threadIdx.x;
    if (e < NE) atomicAdd(&count[ei[NE + e]], 1);
}

__global__ __launch_bounds__(1024) void k_scan(const int* count, int* rowptr) {
    __shared__ int wsum[16];
    __shared__ int carry;
    int tid = threadIdx.x;
    if (tid == 0) { carry = 0; rowptr[0] = 0; }
    __syncthreads();
    for (int base = 0; base < NN; base += 1024) {
        int i = base + tid;
        int v = (i < NN) ? count[i] : 0;
        int lane = tid & 63, wid = tid >> 6;
        int xs = v;
        #pragma unroll
        for (int off = 1; off < 64; off <<= 1) {
            int y = __shfl_up(xs, off);
            if (lane >= off) xs += y;
        }
        if (lane == 63) wsum[wid] = xs;
        __syncthreads();
        if (wid == 0 && lane < 16) {
            int s = wsum[lane];
            #pragma unroll
            for (int off = 1; off < 16; off <<= 1) {
                int y = __shfl_up(s, off);
                if (lane >= off) s += y;
            }
            wsum[lane] = s;
        }
        __syncthreads();
        int prefix = carry + (wid ? wsum[wid-1] : 0);
        if (i < NN) rowptr[i+1] = prefix + xs;
        __syncthreads();
        if (tid == 0) carry += wsum[15];
        __syncthreads();
    }
}

__global__ void k_fill(const int* ei, const float* ew, const int* rowptr,
                       int* cursor, int* col, float* val) {
    int e = blockIdx.x*blockDim.x + threadIdx.x;
    if (e < NE) {
        int src = ei[e];
        int dst = ei[NE + e];
        int p = rowptr[dst] + atomicAdd(&cursor[dst], 1);
        col[p] = src;
        val[p] = ew[e];          // raw weight; normalized after deg
    }
}

__global__ void k_deg(const int* rowptr, const float* val, float* dinv) {
    int n = blockIdx.x*blockDim.x + threadIdx.x;
    if (n >= NN) return;
    float d = 1.0f;              // self loop weight
    int beg = rowptr[n], end = rowptr[n+1];
    for (int j = beg; j < end; ++j) d += val[j];
    dinv[n] = (d > 0.f) ? 1.0f/sqrtf(d) : 0.f;
}

__global__ void k_norm(const int* rowptr, const int* col, const float* dinv, float* val) {
    int n = blockIdx.x*blockDim.x + threadIdx.x;
    if (n >= NN) return;
    float dn = dinv[n];
    int beg = rowptr[n], end = rowptr[n+1];
    for (int j = beg; j < end; ++j) val[j] = dinv[col[j]] * val[j] * dn;
}

// ---------------- fused gate weights ----------------
// per gate g (base g*320): [0..47] W' = W@L_top (f*16+c), [48..63] b' = b@L_top + lb,
// [64..319] L_bot (k*16+c)

__global__ void k_fuse(const float* Wz, const float* bz, const float* Lz, const float* lbz,
                       const float* Wr, const float* br, const float* Lr, const float* lbr,
                       const float* Wh, const float* bh, const float* Lh, const float* lbh,
                       float* fused) {
    int tid = threadIdx.x;
    const float* W[3]  = {Wz, Wr, Wh};
    const float* bb[3] = {bz, br, bh};
    const float* L[3]  = {Lz, Lr, Lh};
    const float* lb[3] = {lbz, lbr, lbh};
    for (int g = 0; g < 3; ++g) {
        float* outp = fused + g*320;
        if (tid < 48) {
            int f = tid >> 4, c = tid & 15;
            float s = 0.f;
            for (int k = 0; k < 16; ++k) s += W[g][f*16+k] * L[g][k*16+c];
            outp[tid] = s;
        }
        if (tid < 16) {
            float s = 0.f;
            for (int k = 0; k < 16; ++k) s += bb[g][k] * L[g][k*16+tid];
            outp[48+tid] = s + lb[g][tid];
        }
        {
            int k = tid >> 4, c = tid & 15;
            outp[64 + tid] = L[g][(16+k)*16 + c];
        }
    }
}

// ---------------- x repack: xp[t][n][b] = float4(x[b,t,n,0..2], 0) ----------------

__global__ __launch_bounds__(256) void k_xpad(const float* x, float4* xp) {
    int idx = blockIdx.x*blockDim.x + threadIdx.x;
    if (idx >= NN*NT) return;
    int n = idx % NN;
    int t = idx / NN;
    #pragma unroll
    for (int b = 0; b < NB; ++b) {
        int base = ((b*NT + t)*NN + n)*NF;
        float4 o; o.x = x[base]; o.y = x[base+1]; o.z = x[base+2]; o.w = 0.f;
        xp[(t*NN + n)*NB + b] = o;
    }
}

// ---------------- aggregation: agg[t][b][n] = (A_hat x_t)[b,n,:] ----------------

__global__ __launch_bounds__(256) void k_agg(const float4* xp, const int* rowptr, const int* col,
                                             const float* val, const float* dinv, float4* agg) {
    int idx = blockIdx.x*blockDim.x + threadIdx.x;
    if (idx >= NN*NT) return;
    int n = idx % NN;
    int t = idx / NN;
    float di = dinv[n];
    float dsq = di*di;                 // self-loop: w=1, norm = dinv[n]^2
    float ax[NB], ay[NB], az[NB];
    int sbase = (t*NN + n)*NB;
    #pragma unroll
    for (int b = 0; b < NB; ++b) {
        float4 v = xp[sbase + b];
        ax[b] = dsq*v.x; ay[b] = dsq*v.y; az[b] = dsq*v.z;
    }
    int beg = rowptr[n], end = rowptr[n+1];
    int j = beg;
    for (; j + 1 < end; j += 2) {       // 2x unroll: 8 independent gathers in flight
        int s0 = col[j],   s1 = col[j+1];
        float nv0 = val[j], nv1 = val[j+1];
        int g0 = (t*NN + s0)*NB, g1 = (t*NN + s1)*NB;
        #pragma unroll
        for (int b = 0; b < NB; ++b) {
            float4 v0 = xp[g0 + b];
            float4 v1 = xp[g1 + b];
            ax[b] += nv0*v0.x + nv1*v1.x;
            ay[b] += nv0*v0.y + nv1*v1.y;
            az[b] += nv0*v0.z + nv1*v1.z;
        }
    }
    if (j < end) {
        int s = col[j];
        float nv = val[j];
        int gb = (t*NN + s)*NB;
        #pragma unroll
        for (int b = 0; b < NB; ++b) {
            float4 v = xp[gb + b];
            ax[b] += nv*v.x; ay[b] += nv*v.y; az[b] += nv*v.z;
        }
    }
    #pragma unroll
    for (int b = 0; b < NB; ++b) {
        float4 o; o.x = ax[b]; o.y = ay[b]; o.z = az[b]; o.w = 0.f;
        agg[(t*NB + b)*NN + n] = o;
    }
}

// ---------------- fused GRU: 16 lanes per (b,n), one lane per channel c ----------------
// Per-lane state: Hv (1 float) + weight COLUMNS in registers (static indices only).
// k-sum over H uses __shfl(Hv, k, 16) broadcast within the 16-lane group.
// 640K threads = 10000 waves -> ~10 waves/SIMD (vs 0.6 before). No spill possible.

__global__ __launch_bounds__(256) void k_gru16(const float* fused, const float4* agg, float* H) {
    int tid = blockIdx.x*blockDim.x + threadIdx.x;
    int gid = tid >> 4;          // (b,n) group
    int c   = tid & 15;          // channel
    if (gid >= NB*NN) return;
    int b = gid / NN, n = gid % NN;

    // per-lane weight columns (L2-cached broadcast loads, 60 scalars)
    float wz0 = fused[c],       wz1 = fused[16+c],  wz2 = fused[32+c],  bz = fused[48+c];
    float wr0 = fused[320+c],   wr1 = fused[336+c], wr2 = fused[352+c], br = fused[368+c];
    float wh0 = fused[640+c],   wh1 = fused[656+c], wh2 = fused[672+c], bh = fused[688+c];
    float Lz[16], Lr[16], Lh[16];
    #pragma unroll
    for (int k = 0; k < 16; ++k) {
        Lz[k] = fused[ 64 + k*16 + c];
        Lr[k] = fused[384 + k*16 + c];
        Lh[k] = fused[704 + k*16 + c];
    }

    float Hv = 0.f;
    const float4* ap = agg + (size_t)b*NN + n;
    for (int t = 0; t < NT; ++t) {
        float4 A = ap[(size_t)t*NB*NN];   // same addr for all 16 lanes -> HW broadcast
        float z = fmaf(A.x, wz0, fmaf(A.y, wz1, fmaf(A.z, wz2, bz)));
        float r = fmaf(A.x, wr0, fmaf(A.y, wr1, fmaf(A.z, wr2, br)));
        #pragma unroll
        for (int k = 0; k < 16; ++k) {
            float hk = __shfl(Hv, k, 16);
            z = fmaf(hk, Lz[k], z);
            r = fmaf(hk, Lr[k], r);
        }
        z = 1.f/(1.f + expf(-z));
        r = 1.f/(1.f + expf(-r));
        float rH = Hv * r;
        float ht = fmaf(A.x, wh0, fmaf(A.y, wh1, fmaf(A.z, wh2, bh)));
        #pragma unroll
        for (int k = 0; k < 16; ++k) {
            float hk = __shfl(rH, k, 16);
            ht = fmaf(hk, Lh[k], ht);
        }
        Hv = z*Hv + (1.f - z)*tanhf(ht);
    }
    H[(size_t)gid*NC + c] = Hv;   // lanes write consecutive floats -> coalesced
}

// ---------------- head: H(4,160000) @ W1(160000,512), split-K, float4 loads ----------------

__global__ __launch_bounds__(256) void k_head1(const float* H, const float* W1, float* part) {
    __shared__ float sH[NB][HCHUNK];
    int chunk = blockIdx.x;
    int i0 = chunk * HCHUNK;
    for (int i = threadIdx.x; i < NB*HCHUNK; i += 256) {
        int b = i / HCHUNK, r = i % HCHUNK;
        sH[b][r] = H[b*FLAT + i0 + r];
    }
    __syncthreads();
    int half = threadIdx.x >> 7;        // which row parity this thread sums
    int jj = (threadIdx.x & 127) * 4;   // column group
    const float* Wb = W1 + (size_t)i0*HID + jj;
    float acc[NB][4] = {};
    for (int r0 = half; r0 < HCHUNK; r0 += 16) {
        float4 w0 = *(const float4*)(Wb + (size_t)(r0     )*HID);
        float4 w1 = *(const float4*)(Wb + (size_t)(r0 +  2)*HID);
        float4 w2 = *(const float4*)(Wb + (size_t)(r0 +  4)*HID);
        float4 w3 = *(const float4*)(Wb + (size_t)(r0 +  6)*HID);
        float4 w4 = *(const float4*)(Wb + (size_t)(r0 +  8)*HID);
        float4 w5 = *(const float4*)(Wb + (size_t)(r0 + 10)*HID);
        float4 w6 = *(const float4*)(Wb + (size_t)(r0 + 12)*HID);
        float4 w7 = *(const float4*)(Wb + (size_t)(r0 + 14)*HID);
        #pragma unroll
        for (int b = 0; b < NB; ++b) {
            float h0 = sH[b][r0],    h1 = sH[b][r0+2],  h2 = sH[b][r0+4],  h3 = sH[b][r0+6];
            float h4 = sH[b][r0+8],  h5 = sH[b][r0+10], h6 = sH[b][r0+12], h7 = sH[b][r0+14];
            acc[b][0] += h0*w0.x + h1*w1.x + h2*w2.x + h3*w3.x + h4*w4.x + h5*w5.x + h6*w6.x + h7*w7.x;
            acc[b][1] += h0*w0.y + h1*w1.y + h2*w2.y + h3*w3.y + h4*w4.y + h5*w5.y + h6*w6.y + h7*w7.y;
            acc[b][2] += h0*w0.z + h1*w1.z + h2*w2.z + h3*w3.z + h4*w4.z + h5*w5.z + h6*w6.z + h7*w7.z;
            acc[b][3] += h0*w0.w + h1*w1.w + h2*w2.w + h3*w3.w + h4*w4.w + h5*w5.w + h6*w6.w + h7*w7.w;
        }
    }
    int pc = chunk*2 + half;
    #pragma unroll
    for (int q = 0; q < 4; ++q)
        #pragma unroll
        for (int b = 0; b < NB; ++b)
            part[((size_t)pc*HID + jj + q)*NB + b] = acc[b][q];
}

// phase 1: split the 1000-chunk sum 16 ways, float4-wide (8192 threads)
__global__ void k_reduce1(const float4* part, float4* part2) {
    int idx = blockIdx.x*blockDim.x + threadIdx.x;   // 0 .. RSPLIT*512-1
    if (idx >= RSPLIT*512) return;
    int k = idx >> 9;            // split index
    int jq = idx & 511;          // float4 lane within the 2048-float row
    int c0 = k*RSPAN;
    int c1 = c0 + RSPAN; if (c1 > NPART) c1 = NPART;
    float4 s = make_float4(0.f, 0.f, 0.f, 0.f);
    for (int c = c0; c < c1; ++c) {
        float4 v = part[(size_t)c*512 + jq];
        s.x += v.x; s.y += v.y; s.z += v.z; s.w += v.w;
    }
    part2[k*512 + jq] = s;
}

// phase 2 + final head, one block: h1 = leaky(sum + b1); out = h1 @ W2 + b2
__global__ __launch_bounds__(256) void k_reduce2final(const float* part2, const float* b1,
                                                      const float* W2, const float* b2, float* out) {
    __shared__ float sH1[HID*NB];        // [j*4+b]
    __shared__ float sred[4][8];
    int tid = threadIdx.x;
    #pragma unroll
    for (int i = 0; i < 8; ++i) {
        int jb = tid + i*256;
        int j = jb >> 2;
        float s = 0.f;
        #pragma unroll
        for (int k = 0; k < RSPLIT; ++k) s += part2[k*(HID*NB) + jb];
        s += b1[j];
        s = (s > 0.f) ? s : 0.01f*s;     // LeakyReLU(0.01)
        sH1[jb] = s;
    }
    __syncthreads();
    float p[8] = {};                      // [b*2+o]
    #pragma unroll
    for (int rep = 0; rep < 2; ++rep) {
        int j = tid + rep*256;
        float w0 = W2[j*NOUT], w1 = W2[j*NOUT+1];
        #pragma unroll
        for (int b = 0; b < NB; ++b) {
            float hv = sH1[j*4 + b];
            p[b*2]   += hv*w0;
            p[b*2+1] += hv*w1;
        }
    }
    int lane = tid & 63, wid = tid >> 6;
    #pragma unroll
    for (int i = 0; i < 8; ++i) {
        #pragma unroll
        for (int off = 32; off > 0; off >>= 1) p[i] += __shfl_xor(p[i], off);
    }
    if (lane == 0)
        #pragma unroll
        for (int i = 0; i < 8; ++i) sred[wid][i] = p[i];
    __syncthreads();
    if (tid < 8) {
        float s = sred[0][tid] + sred[1][tid] + sred[2][tid] + sred[3][tid];
        out[tid] = s + b2[tid & 1];
    }
}

// ---------------- launch ----------------

extern "C" void kernel_launch(void* const* d_in, const int* in_sizes, int n_in,
                              void* d_out, int out_size, void* d_ws, size_t ws_size,
                              hipStream_t stream) {
    const float* x   = (const float*)d_in[0];
    const int*   ei  = (const int*)d_in[1];
    const float* ew  = (const float*)d_in[2];
    const float* Wz  = (const float*)d_in[3];
    const float* bz  = (const float*)d_in[4];
    const float* Lz  = (const float*)d_in[5];
    const float* lbz = (const float*)d_in[6];
    const float* Wr  = (const float*)d_in[7];
    const float* br  = (const float*)d_in[8];
    const float* Lr  = (const float*)d_in[9];
    const float* lbr = (const float*)d_in[10];
    const float* Wh  = (const float*)d_in[11];
    const float* bh  = (const float*)d_in[12];
    const float* Lh  = (const float*)d_in[13];
    const float* lbh = (const float*)d_in[14];
    const float* W1  = (const float*)d_in[15];
    const float* b1  = (const float*)d_in[16];
    const float* W2  = (const float*)d_in[17];
    const float* b2  = (const float*)d_in[18];
    float* out = (float*)d_out;

    char* base = (char*)d_ws;
    size_t off = 0;
    auto alloc = [&](size_t bytes) -> char* {
        char* p = base + off;
        off = (off + bytes + 255) & ~(size_t)255;
        return p;
    };
    float*  fused  = (float*)alloc(960*sizeof(float));
    float*  dinv   = (float*)alloc(NN*sizeof(float));
    int*    count  = (int*)  alloc(NN*sizeof(int));
    int*    rowptr = (int*)  alloc((NN+1)*sizeof(int));
    int*    cursor = (int*)  alloc(NN*sizeof(int));
    int*    col    = (int*)  alloc(NE*sizeof(int));
    float*  val    = (float*)alloc(NE*sizeof(float));
    float4* xp     = (float4*)alloc((size_t)NT*NN*NB*sizeof(float4));
    float4* agg    = (float4*)alloc((size_t)NT*NB*NN*sizeof(float4));
    float*  H      = (float*)alloc((size_t)NB*NN*NC*sizeof(float));
    float*  part   = (float*)alloc((size_t)NPART*HID*NB*sizeof(float));
    float*  part2  = (float*)alloc((size_t)RSPLIT*HID*NB*sizeof(float));
    (void)ws_size; (void)n_in; (void)in_sizes; (void)out_size;

    k_init<<<(NN+255)/256, 256, 0, stream>>>(count, cursor);
    k_count<<<(NE+255)/256, 256, 0, stream>>>(ei, count);
    k_scan<<<1, 1024, 0, stream>>>(count, rowptr);
    k_fill<<<(NE+255)/256, 256, 0, stream>>>(ei, ew, rowptr, cursor, col, val);
    k_deg<<<(NN+255)/256, 256, 0, stream>>>(rowptr, val, dinv);
    k_norm<<<(NN+255)/256, 256, 0, stream>>>(rowptr, col, dinv, val);
    k_fuse<<<1, 256, 0, stream>>>(Wz, bz, Lz, lbz, Wr, br, Lr, lbr, Wh, bh, Lh, lbh, fused);
    k_xpad<<<(NN*NT+255)/256, 256, 0, stream>>>(x, xp);
    k_agg<<<(NN*NT+255)/256, 256, 0, stream>>>(xp, rowptr, col, val, dinv, agg);
    k_gru16<<<(NB*NN*16+255)/256, 256, 0, stream>>>(fused, agg, H);
    k_head1<<<NHB, 256, 0, stream>>>(H, W1, part);
    k_reduce1<<<(RSPLIT*512+255)/256, 256, 0, stream>>>((const float4*)part, (float4*)part2);
    k_reduce2final<<<1, 256, 0, stream>>>(part2, b1, W2, b2, out);
}